// Round 8
// baseline (374.478 us; speedup 1.0000x reference)
//
#include <hip/hip_runtime.h>
#include <stdint.h>

// Problem constants
#define BB 2
#define SS 2048
#define HID 2048
#define NH 16
#define DD 128
#define NKV 4

typedef unsigned short u16;
typedef __attribute__((ext_vector_type(8))) short short8;   // 8 x bf16 (4 VGPRs) MFMA A/B frag
typedef __attribute__((ext_vector_type(4))) float f32x4;    // MFMA C/D frag

#if __has_builtin(__builtin_amdgcn_exp2f)
#define EXP2(x) __builtin_amdgcn_exp2f(x)
#else
#define EXP2(x) exp2f(x)
#endif

__device__ __forceinline__ u16 f2bf(float x) {
    union { float f; unsigned u; } v; v.f = x;
    unsigned u = v.u;
    return (u16)((u + 0x7FFFu + ((u >> 16) & 1u)) >> 16);   // RNE
}

// async global->LDS, 16B per lane. lds ptr must be wave-uniform (HW adds lane*16).
__device__ __forceinline__ void async_lds16(const void* g, void* l) {
    __builtin_amdgcn_global_load_lds(
        (const __attribute__((address_space(1))) void*)(uintptr_t)g,
        (__attribute__((address_space(3))) void*)(uintptr_t)l,
        16, 0, 0);
}

// ---------------- prep: fp32->bf16 converts (q,k,v) + all weight transposes, one launch ------
__global__ __launch_bounds__(256) void k_prep(const float* __restrict__ query,
                                              const float* __restrict__ key,
                                              const float* __restrict__ value,
                                              const float* __restrict__ Wq,
                                              const float* __restrict__ Wk,
                                              const float* __restrict__ Wv,
                                              const float* __restrict__ Wo,
                                              u16* __restrict__ qbf,
                                              u16* __restrict__ kbf,
                                              u16* __restrict__ vbf,
                                              u16* __restrict__ Wt,
                                              u16* __restrict__ Wot) {
    __shared__ float tile[32][33];
    int x = blockIdx.x;
    if (x < 24576) {
        const float* in; u16* out;
        if (x < 8192)       { in = query; out = qbf; }
        else if (x < 16384) { in = key;   out = kbf; x -= 8192; }
        else                { in = value; out = vbf; x -= 16384; }
        const int i = x * 256 + threadIdx.x;
        float4 v = ((const float4*)in)[i];
        uint2 o;
        o.x = (unsigned)f2bf(v.x) | ((unsigned)f2bf(v.y) << 16);
        o.y = (unsigned)f2bf(v.z) | ((unsigned)f2bf(v.w) << 16);
        ((uint2*)out)[i] = o;
        return;
    }
    const int v_ = x - 24576;            // 0..10239
    const int ty = v_ / 160;             // k-tile 0..63
    const int xt = v_ - ty * 160;        // n-tile 0..159
    const float* src; u16* dst; int N, n0;
    if (xt < 64)      { src = Wq; dst = Wt;                          N = 2048; n0 = xt * 32; }
    else if (xt < 80) { src = Wk; dst = Wt + (size_t)2048 * 2048;    N = 512;  n0 = (xt - 64) * 32; }
    else if (xt < 96) { src = Wv; dst = Wt + (size_t)2560 * 2048;    N = 512;  n0 = (xt - 80) * 32; }
    else              { src = Wo; dst = Wot;                         N = 2048; n0 = (xt - 96) * 32; }
    const int k0 = ty * 32;
    const int c = threadIdx.x & 31, r = threadIdx.x >> 5;
#pragma unroll
    for (int i = 0; i < 32; i += 8)
        tile[r + i][c] = src[(size_t)(k0 + r + i) * N + n0 + c];
    __syncthreads();
#pragma unroll
    for (int i = 0; i < 32; i += 8)
        dst[(size_t)(n0 + r + i) * 2048 + k0 + c] = f2bf(tile[c][r + i]);
}

// ================= 128x128 / BK=32 TRIPLE-buffered GEMM core, counted vmcnt ==============
// 4 waves (2M x 2N), per-wave 64x64 output = acc[4][4]. LDS 48 KB -> 3 blocks/CU resident
// (768-block qkv grid = every block resident, no generation tail).
// Prefetch distance 2: prologue issues T0,T1; iter t does {s_waitcnt vmcnt(4); s_barrier}
// (own tile-t loads landed, collective via barrier; tile-(t+1)'s 4 loads REMAIN IN FLIGHT
// across the barrier = T3/T4 counted-vmcnt lever), then issues T(t+2) into buf (t+2)%3
// (its readers finished at iter t-1, two barriers ago). Tile-t loads thus get two full
// iterations of latency cover instead of one compute phase.
// BK=32 swizzle: 4 chunks of 16B per 64B row; slot = chunk ^ ((row>>1)&3) — the >>1 key
// spreads 16 consecutive rows over all 8 bank-groups (2 lanes/bank = free); a row&3 key
// would be 4-way conflicted at 64B stride. Linear LDS dest + pre-swizzled global source.
__device__ __forceinline__ void gemm128_loop(const u16* __restrict__ gA,
                                             const u16* __restrict__ gB,
                                             const int K, char* smem,
                                             const int wave, const int lane,
                                             f32x4 (&acc)[4][4]) {
    const int r = lane & 15, q4 = lane >> 4;
    const int wm = (wave & 1) * 64, wn = (wave >> 1) * 64;
    u16* As = (u16*)smem;                  // 3 bufs x 8 KB
    u16* Bs = (u16*)(smem + 24576);        // 3 bufs x 8 KB

    // frag offsets (elements): row ar, k-slot q4; key (ar>>1)&3 == (r>>1)&3 (wm+i*16 is 16-aligned)
    int aoff[4], boff[4];
#pragma unroll
    for (int i = 0; i < 4; i++) {
        const int ar = wm + i * 16 + r;
        aoff[i] = ar * 32 + ((q4 ^ ((r >> 1) & 3)) << 3);
        const int br = wn + i * 16 + r;
        boff[i] = br * 32 + ((q4 ^ ((r >> 1) & 3)) << 3);
    }

    const int nt = K >> 5;

    // 4 loads/wave/tile: each load = 16 rows x 64 B (1 KB). Wave w covers rows w*16..+15
    // and 64+w*16..+15 for both A and B. Linear LDS dest (HW adds lane*16).
#define STG32(buf, T) do {                                                                   \
        async_lds16(gA + (size_t)(wave * 16) * K + (size_t)(T) * 32,                         \
                    smem + (buf) * 8192 + (wave * 16) * 64);                                 \
        async_lds16(gA + (size_t)(64 + wave * 16) * K + (size_t)(T) * 32,                    \
                    smem + (buf) * 8192 + (64 + wave * 16) * 64);                            \
        async_lds16(gB + (size_t)(wave * 16) * K + (size_t)(T) * 32,                         \
                    smem + 24576 + (buf) * 8192 + (wave * 16) * 64);                         \
        async_lds16(gB + (size_t)(64 + wave * 16) * K + (size_t)(T) * 32,                    \
                    smem + 24576 + (buf) * 8192 + (64 + wave * 16) * 64);                    \
    } while (0)

    STG32(0, 0);
    STG32(1, 1);

    int cur = 0;
    for (int t = 0; t < nt; t++) {
        // counted wait: own tile-t loads landed (collective via barrier); t+1's 4 stay in flight
        if (t + 1 < nt) asm volatile("s_waitcnt vmcnt(4)\ns_barrier" ::: "memory");
        else            asm volatile("s_waitcnt vmcnt(0)\ns_barrier" ::: "memory");
        if (t + 2 < nt) {
            int nb = cur + 2; if (nb >= 3) nb -= 3;
            STG32(nb, t + 2);
        }

        const u16* Ab = As + cur * 4096;   // 8 KB = 4096 u16
        const u16* Bb = Bs + cur * 4096;
        short8 Af[4], Bf[4];
#pragma unroll
        for (int i = 0; i < 4; i++) {
            Af[i] = *(const short8*)(Ab + aoff[i]);
            Bf[i] = *(const short8*)(Bb + boff[i]);
        }
        __builtin_amdgcn_s_setprio(1);
#pragma unroll
        for (int i = 0; i < 4; i++)
#pragma unroll
            for (int j = 0; j < 4; j++)
                acc[i][j] = __builtin_amdgcn_mfma_f32_16x16x32_bf16(Af[i], Bf[j], acc[i][j], 0, 0, 0);
        __builtin_amdgcn_s_setprio(0);

        cur = (cur == 2) ? 0 : cur + 1;
    }
#undef STG32
}

// ---------------- fused QKV projection GEMM, 128x128 tile, 768 blocks (all resident, 3/CU) --
// bn<16: Q-proj (RoPE+scale -> qro); bn 16..19: K-proj (RoPE -> kro); bn 20..23: V (-> vtr).
__global__ __launch_bounds__(256, 3) void k_gemm_qkv(const u16* __restrict__ qbf,
                                                     const u16* __restrict__ kbf,
                                                     const u16* __restrict__ vbf,
                                                     const u16* __restrict__ Wt,   // [3072][2048] bf16
                                                     const float* __restrict__ bq,
                                                     const float* __restrict__ bk,
                                                     const float* __restrict__ bv,
                                                     const float* __restrict__ fc,
                                                     const float* __restrict__ fs,
                                                     u16* __restrict__ qro,
                                                     u16* __restrict__ kro,
                                                     u16* __restrict__ vtr) {
    __shared__ char smem[49152];
    const int tid = threadIdx.x;
    const int lane = tid & 63, wave = tid >> 6;
    const int r = lane & 15, q4 = lane >> 4;
    const int wm = (wave & 1) * 64, wn = (wave >> 1) * 64;

    // XCD-chunked bijective remap: 768 blocks = 8 XCDs x 96 (bx-fastest: A-panel L2 reuse)
    const int linear = blockIdx.y * 24 + blockIdx.x;
    const int nb = (linear & 7) * 96 + (linear >> 3);
    const int bn = nb % 24;
    const int bm = (nb / 24) * 128;

    const u16* A = (bn < 16) ? qbf : (bn < 20) ? kbf : vbf;

    // staging map: srow = lane>>2 (row within 16-row group), chunk = lane&3, key (srow>>1)&3
    const int srow = lane >> 2;
    const int c0 = ((lane & 3) ^ ((srow >> 1) & 3)) * 8;
    const u16* gA = A  + (size_t)(bm + srow) * 2048 + c0;
    const u16* gB = Wt + (size_t)(bn * 128 + srow) * 2048 + c0;

    f32x4 acc[4][4] = {};
    gemm128_loop(gA, gB, 2048, smem, wave, lane, acc);

    // all waves done reading LDS before ep-scratch aliasing
    __syncthreads();

    // ---------------- fused epilogues (proven round-0 geometry) ------
    float* Ep = (float*)smem;
    if (bn < 20) {
        const bool isQ = (bn < 16);
        const float qsc = isQ ? 0.08838834764831845f * 1.4426950408889634f : 1.0f;
        const float* bias = isQ ? bq : bk;
        const int head = isQ ? bn : (bn - 16);
        u16* base = isQ ? qro : kro;
        const int nheads = isQ ? NH : NKV;

        float* ep = Ep + wave * 1280;           // 64 rows x 20 words (2-way on write = free)
        const int rowg = bm + wm + lane;        // this lane's s-row (read phase)
        const int s = rowg & 2047, bidx = rowg >> 11;
        const float* fcp0 = fc + s * 64;
        const float* fsp0 = fs + s * 64;

#pragma unroll
        for (int j = 0; j < 4; j++) {
            const float bcol = bias[head * 128 + wn + j * 16 + r];
#pragma unroll
            for (int i = 0; i < 4; i++)
#pragma unroll
                for (int g = 0; g < 4; g++)
                    ep[(i * 16 + q4 * 4 + g) * 20 + r] = acc[i][j][g] + bcol;
            float4 x0 = *(float4*)(ep + lane * 20 + 0);
            float4 x1 = *(float4*)(ep + lane * 20 + 4);
            float4 x2 = *(float4*)(ep + lane * 20 + 8);
            float4 x3 = *(float4*)(ep + lane * 20 + 12);
            const int d0 = wn + j * 16;
            const int ii0 = d0 >> 1;
            float4 ca = *(const float4*)(fcp0 + ii0);
            float4 cb = *(const float4*)(fcp0 + ii0 + 4);
            float4 sa = *(const float4*)(fsp0 + ii0);
            float4 sb = *(const float4*)(fsp0 + ii0 + 4);
            float o[16];
            o[0]  = (x0.x * ca.x - x0.y * sa.x) * qsc;  o[1]  = (x0.x * sa.x + x0.y * ca.x) * qsc;
            o[2]  = (x0.z * ca.y - x0.w * sa.y) * qsc;  o[3]  = (x0.z * sa.y + x0.w * ca.y) * qsc;
            o[4]  = (x1.x * ca.z - x1.y * sa.z) * qsc;  o[5]  = (x1.x * sa.z + x1.y * ca.z) * qsc;
            o[6]  = (x1.z * ca.w - x1.w * sa.w) * qsc;  o[7]  = (x1.z * sa.w + x1.w * ca.w) * qsc;
            o[8]  = (x2.x * cb.x - x2.y * sb.x) * qsc;  o[9]  = (x2.x * sb.x + x2.y * cb.x) * qsc;
            o[10] = (x2.z * cb.y - x2.w * sb.y) * qsc;  o[11] = (x2.z * sb.y + x2.w * cb.y) * qsc;
            o[12] = (x3.x * cb.z - x3.y * sb.z) * qsc;  o[13] = (x3.x * sb.z + x3.y * cb.z) * qsc;
            o[14] = (x3.z * cb.w - x3.w * sb.w) * qsc;  o[15] = (x3.z * sb.w + x3.w * cb.w) * qsc;
            unsigned w0 = (unsigned)f2bf(o[0])  | ((unsigned)f2bf(o[1])  << 16);
            unsigned w1 = (unsigned)f2bf(o[2])  | ((unsigned)f2bf(o[3])  << 16);
            unsigned w2 = (unsigned)f2bf(o[4])  | ((unsigned)f2bf(o[5])  << 16);
            unsigned w3 = (unsigned)f2bf(o[6])  | ((unsigned)f2bf(o[7])  << 16);
            unsigned w4 = (unsigned)f2bf(o[8])  | ((unsigned)f2bf(o[9])  << 16);
            unsigned w5 = (unsigned)f2bf(o[10]) | ((unsigned)f2bf(o[11]) << 16);
            unsigned w6 = (unsigned)f2bf(o[12]) | ((unsigned)f2bf(o[13]) << 16);
            unsigned w7 = (unsigned)f2bf(o[14]) | ((unsigned)f2bf(o[15]) << 16);
            u16* dst = base + (((size_t)(bidx * nheads + head) * SS + s) << 7) + d0;
            *(uint4*)dst = make_uint4(w0, w1, w2, w3);
            *(uint4*)(dst + 8) = make_uint4(w4, w5, w6, w7);
        }
    } else {
        // V path: convert + transpose to vtr[B][KV][D][S]
#pragma unroll
        for (int j = 0; j < 4; j++) {
            const int col = bn * 128 + wn + j * 16 + r - 2560;
            const int d = col & 127, kv = col >> 7;
            const float bb = bv[col];
#pragma unroll
            for (int i = 0; i < 4; i++) {
                const int row0 = bm + wm + i * 16 + q4 * 4;
                const int s0 = row0 & 2047, b = row0 >> 11;
                uint2 o;
                o.x = (unsigned)f2bf(acc[i][j][0] + bb) | ((unsigned)f2bf(acc[i][j][1] + bb) << 16);
                o.y = (unsigned)f2bf(acc[i][j][2] + bb) | ((unsigned)f2bf(acc[i][j][3] + bb) << 16);
                *(uint2*)(vtr + ((size_t)(b * NKV + kv) * DD + d) * SS + s0) = o;
            }
        }
    }
}

// ---------------- O-projection GEMM, 128x128 tile, 512 blocks -----
__global__ __launch_bounds__(256, 3) void k_gemm_bt(const u16* __restrict__ A,
                                                    const u16* __restrict__ Bt,
                                                    const float* __restrict__ bias,
                                                    float* __restrict__ C,
                                                    int M, int N, int K) {
    __shared__ char smem[49152];
    const int tid = threadIdx.x;
    const int lane = tid & 63, wave = tid >> 6;
    const int r = lane & 15, q4 = lane >> 4;
    const int wm = (wave & 1) * 64, wn = (wave >> 1) * 64;

    // 512 blocks = 8 XCDs x 64 chunk (bijective, bx-fastest)
    const int linear = blockIdx.y * 16 + blockIdx.x;
    const int nb = (linear & 7) * 64 + (linear >> 3);
    const int bn0 = (nb & 15) * 128;
    const int bm0 = (nb >> 4) * 128;

    const int srow = lane >> 2;
    const int c0 = ((lane & 3) ^ ((srow >> 1) & 3)) * 8;
    const u16* gA = A  + (size_t)(bm0 + srow) * K + c0;
    const u16* gB = Bt + (size_t)(bn0 + srow) * K + c0;

    f32x4 acc[4][4] = {};
    gemm128_loop(gA, gB, K, smem, wave, lane, acc);

#pragma unroll
    for (int j = 0; j < 4; j++) {
        const int col = bn0 + wn + j * 16 + r;
        const float bb = bias[col];
#pragma unroll
        for (int i = 0; i < 4; i++) {
            const int row = bm0 + wm + i * 16 + q4 * 4;
#pragma unroll
            for (int g = 0; g < 4; g++)
                C[(size_t)(row + g) * N + col] = acc[i][j][g] + bb;
        }
    }
}

// ---------------- flash attention: KVBLK=64, double-buffered, 1 barrier / 64 keys ----------
// (byte-identical to round 7 — hardware-verified passing)
__global__ __launch_bounds__(256) void k_attn(const u16* __restrict__ Q,   // [B*H][S][D] (scaled)
                                              const u16* __restrict__ K_,  // [B*KV][S][D]
                                              const u16* __restrict__ V_,  // [B*KV][D][S]
                                              u16* __restrict__ Ctx) {     // [B*S][H*D]
    __shared__ u16 Ks[2][64 * 128];    // 2 x 16 KB
    __shared__ u16 Vs[2][2 * 128 * 32];// 2 x 16 KB, layout [half][d 0..127][32 keys]
    __shared__ u16 Pb[4][32 * 40];     // 10 KB, 80B row stride (free 2-way)

    const int tid = threadIdx.x;
    const int lane = tid & 63, wave = tid >> 6;
    const int bh = blockIdx.x;
    const int b = bh >> 4, h = bh & 15;
    const int kvh = (b << 2) | (h >> 2);
    const int qb = (gridDim.y - 1 - blockIdx.y) * 128;   // heavy-first
    const int qcol = lane & 15, q4 = lane >> 4;
    const int qw = qb + wave * 32;

    const u16* Qg = Q + ((size_t)bh * SS + qw + qcol) * DD;
    short8 qfr[2][4];
#pragma unroll
    for (int qi = 0; qi < 2; qi++)
#pragma unroll
        for (int c = 0; c < 4; c++)
            qfr[qi][c] = *(const short8*)(Qg + qi * 16 * DD + c * 32 + q4 * 8);

    const u16* Kg = K_ + (size_t)kvh * SS * DD;
    const u16* Vg = V_ + (size_t)kvh * DD * SS;

    const int krow = tid >> 4;                    // 0..15 across block (4 rows/wave/load)
    const int kchunk = (tid & 15) ^ (krow & 7);
    const int vd = tid >> 2;                      // 0..63 (16 d-rows/wave/load)
    const int vchunk = (tid & 3) ^ ((vd >> 1) & 3);

    const int nt = (qb + 128) >> 6;
    const int kmax = (nt - 1) * 64;               // clamp prefetch (stay in-bounds)

    f32x4 lacc[2] = {};
    f32x4 oacc[2][8] = {};

    const short8 ones = {0x3F80, 0x3F80, 0x3F80, 0x3F80, 0x3F80, 0x3F80, 0x3F80, 0x3F80};
    u16* pb = &Pb[wave][0];
    unsigned* pb32 = (unsigned*)pb;

    // 8 loads/wave: K rows {0,16,32,48}+krow ; V (half,dblk) x {16 d-rows, 32 keys}
#define STAGE_KV(T, BUF) do {                                                                   \
        const int kb_ = min((T) * 64, kmax);                                                    \
        async_lds16(Kg + (size_t)(kb_ + krow) * DD + kchunk * 8,        &Ks[BUF][0] + wave * 512);        \
        async_lds16(Kg + (size_t)(kb_ + 16 + krow) * DD + kchunk * 8,   &Ks[BUF][0] + 2048 + wave * 512); \
        async_lds16(Kg + (size_t)(kb_ + 32 + krow) * DD + kchunk * 8,   &Ks[BUF][0] + 4096 + wave * 512); \
        async_lds16(Kg + (size_t)(kb_ + 48 + krow) * DD + kchunk * 8,   &Ks[BUF][0] + 6144 + wave * 512); \
        async_lds16(Vg + (size_t)vd * SS + kb_ + vchunk * 8,            &Vs[BUF][0] + wave * 512);        \
        async_lds16(Vg + (size_t)vd * SS + kb_ + 32 + vchunk * 8,       &Vs[BUF][0] + 4096 + wave * 512); \
        async_lds16(Vg + (size_t)(vd + 64) * SS + kb_ + vchunk * 8,     &Vs[BUF][0] + 2048 + wave * 512); \
        async_lds16(Vg + (size_t)(vd + 64) * SS + kb_ + 32 + vchunk * 8,&Vs[BUF][0] + 6144 + wave * 512); \
    } while (0)

    STAGE_KV(0, 0);

    for (int t = 0; t < nt; t++) {
        const int kb = t * 64;
        const int cur = t & 1;
        // collective: all waves' tile-t loads landed AND all done computing t-1
        asm volatile("s_waitcnt vmcnt(0)\n\ts_barrier" ::: "memory");
        if (t + 1 < nt) STAGE_KV(t + 1, cur ^ 1);

#pragma unroll
        for (int hh = 0; hh < 2; hh++) {
            const int kbh = kb + hh * 32;
            if (kbh <= qw + 31) {                      // wave-uniform causal skip
                const u16* Ksc = &Ks[cur][hh * 32 * 128];
                const u16* Vsc = &Vs[cur][hh * 4096];

                f32x4 sc[2][2] = {};
                __builtin_amdgcn_s_setprio(1);
#pragma unroll
                for (int kt = 0; kt < 2; kt++) {
                    const int kr = kt * 16 + qcol;
#pragma unroll
                    for (int c = 0; c < 4; c++) {
                        short8 kf = *(const short8*)(Ksc + kr * 128 + (((c * 4 + q4) ^ (kr & 7)) << 3));
                        sc[kt][0] = __builtin_amdgcn_mfma_f32_16x16x32_bf16(kf, qfr[0][c], sc[kt][0], 0, 0, 0);
                        sc[kt][1] = __builtin_amdgcn_mfma_f32_16x16x32_bf16(kf, qfr[1][c], sc[kt][1], 0, 0, 0);
                    }
                }
                __builtin_amdgcn_s_setprio(0);

                if (kbh + 32 > qw) {                   // diagonal halves only
#pragma unroll
                    for (int kt = 0; kt < 2; kt++)
#pragma unroll
                        for (int qi = 0; qi < 2; qi++)
#pragma unroll
                            for (int g = 0; g < 4; g++) {
                                const int key = kbh + kt * 16 + q4 * 4 + g;
                                if (key > qw + qi * 16 + qcol) sc[kt][qi][g] = -1e30f;
                            }
                }

                const unsigned sel = 0x07060302u;
#pragma unroll
                for (int qi = 0; qi < 2; qi++) {
                    float p0 = EXP2(sc[0][qi][0]), p1 = EXP2(sc[0][qi][1]);
                    float p2 = EXP2(sc[0][qi][2]), p3 = EXP2(sc[0][qi][3]);
                    float p4 = EXP2(sc[1][qi][0]), p5 = EXP2(sc[1][qi][1]);
                    float p6 = EXP2(sc[1][qi][2]), p7 = EXP2(sc[1][qi][3]);
                    unsigned pk0 = __builtin_amdgcn_perm(__float_as_uint(p1), __float_as_uint(p0), sel);
                    unsigned pk1 = __builtin_amdgcn_perm(__float_as_uint(p3), __float_as_uint(p2), sel);
                    unsigned pk2 = __builtin_amdgcn_perm(__float_as_uint(p5), __float_as_uint(p4), sel);
                    unsigned pk3 = __builtin_amdgcn_perm(__float_as_uint(p7), __float_as_uint(p6), sel);
                    const int row = qi * 16 + qcol;
                    *(uint2*)(pb32 + row * 20 + 2 * q4)     = make_uint2(pk0, pk1);
                    *(uint2*)(pb32 + row * 20 + 8 + 2 * q4) = make_uint2(pk2, pk3);
                }

                short8 pf0 = *(const short8*)(pb + qcol * 40 + q4 * 8);
                short8 pf1 = *(const short8*)(pb + (16 + qcol) * 40 + q4 * 8);

                __builtin_amdgcn_s_setprio(1);
                lacc[0] = __builtin_amdgcn_mfma_f32_16x16x32_bf16(ones, pf0, lacc[0], 0, 0, 0);
                lacc[1] = __builtin_amdgcn_mfma_f32_16x16x32_bf16(ones, pf1, lacc[1], 0, 0, 0);
#pragma unroll
                for (int dt = 0; dt < 8; dt++) {
                    const int vr = dt * 16 + qcol;
                    short8 vfr = *(const short8*)(Vsc + vr * 32 + ((q4 ^ ((vr >> 1) & 3)) << 3));
                    oacc[0][dt] = __builtin_amdgcn_mfma_f32_16x16x32_bf16(vfr, pf0, oacc[0][dt], 0, 0, 0);
                    oacc[1][dt] = __builtin_amdgcn_mfma_f32_16x16x32_bf16(vfr, pf1, oacc[1][dt], 0, 0, 0);
                }
                __builtin_amdgcn_s_setprio(0);
            }
        }
    }
#undef STAGE_KV

#pragma unroll
    for (int qi = 0; qi < 2; qi++) {
        const float inv = 1.0f / lacc[qi][0];
        u16* outp = Ctx + ((size_t)b * SS + qw + qi * 16 + qcol) * (NH * DD) + h * DD;
#pragma unroll
        for (int dt = 0; dt < 8; dt++) {
            unsigned lo = (unsigned)f2bf(oacc[qi][dt][0] * inv) | ((unsigned)f2bf(oacc[qi][dt][1] * inv) << 16);
            unsigned hi = (unsigned)f2bf(oacc[qi][dt][2] * inv) | ((unsigned)f2bf(oacc[qi][dt][3] * inv) << 16);
            *(uint2*)(outp + dt * 16 + q4 * 4) = make_uint2(lo, hi);
        }
    }
}

extern "C" void kernel_launch(void* const* d_in, const int* in_sizes, int n_in,
                              void* d_out, int out_size, void* d_ws, size_t ws_size,
                              hipStream_t stream) {
    const float* query = (const float*)d_in[0];
    const float* key   = (const float*)d_in[1];
    const float* value = (const float*)d_in[2];
    const float* fc    = (const float*)d_in[4];
    const float* fs    = (const float*)d_in[5];
    const float* Wq    = (const float*)d_in[6];
    const float* bq    = (const float*)d_in[7];
    const float* Wk    = (const float*)d_in[8];
    const float* bk    = (const float*)d_in[9];
    const float* Wv    = (const float*)d_in[10];
    const float* bv    = (const float*)d_in[11];
    const float* Wo    = (const float*)d_in[12];
    const float* bo    = (const float*)d_in[13];
    float* out = (float*)d_out;

    char* w = (char*)d_ws;
    u16* qbf = (u16*)(w);                    // 16 MB  bf16 query [4096][2048]
    u16* kbf = (u16*)(w + 16777216);         // 16 MB
    u16* vbf = (u16*)(w + 33554432);         // 16 MB
    u16* Wt  = (u16*)(w + 50331648);         // 12 MB  [Wq|Wk|Wv]^T bf16 [3072][2048]
    u16* Wot = (u16*)(w + 62914560);         //  8 MB  Wo^T bf16 [2048][2048]
    u16* qro = (u16*)(w + 71303168);         // 16 MB  roped+scaled q bf16 [B][H][S][D]
    u16* kro = (u16*)(w + 88080384);         //  4 MB  roped k bf16 [B][KV][S][D]
    u16* vtr = (u16*)(w + 92274688);         //  4 MB  v bf16 [B][KV][D][S]
    u16* ctx = (u16*)(w + 96468992);         // 16 MB  ctx bf16 [4096][2048]  (end 108 MB)

    k_prep<<<34816, 256, 0, stream>>>(query, key, value, Wq, Wk, Wv, Wo,
                                      qbf, kbf, vbf, Wt, Wot);
    k_gemm_qkv<<<dim3(24, 32), 256, 0, stream>>>(qbf, kbf, vbf, Wt, bq, bk, bv,
                                                 fc, fs, qro, kro, vtr);
    k_attn<<<dim3(32, 16), 256, 0, stream>>>(qro, kro, vtr, ctx);
    k_gemm_bt<<<dim3(16, 32), 256, 0, stream>>>(ctx, Wot, bo, out, 4096, 2048, 2048);
}

// Round 9
// 362.722 us; speedup vs baseline: 1.0324x; 1.0324x over previous
//
#include <hip/hip_runtime.h>
#include <stdint.h>

// Problem constants
#define BB 2
#define SS 2048
#define HID 2048
#define NH 16
#define DD 128
#define NKV 4

typedef unsigned short u16;
typedef __attribute__((ext_vector_type(8))) short short8;   // 8 x bf16 (4 VGPRs) MFMA A/B frag
typedef __attribute__((ext_vector_type(4))) float f32x4;    // MFMA C/D frag

#if __has_builtin(__builtin_amdgcn_exp2f)
#define EXP2(x) __builtin_amdgcn_exp2f(x)
#else
#define EXP2(x) exp2f(x)
#endif

__device__ __forceinline__ u16 f2bf(float x) {
    union { float f; unsigned u; } v; v.f = x;
    unsigned u = v.u;
    return (u16)((u + 0x7FFFu + ((u >> 16) & 1u)) >> 16);   // RNE
}

// async global->LDS, 16B per lane. lds ptr must be wave-uniform (HW adds lane*16).
__device__ __forceinline__ void async_lds16(const void* g, void* l) {
    __builtin_amdgcn_global_load_lds(
        (const __attribute__((address_space(1))) void*)(uintptr_t)g,
        (__attribute__((address_space(3))) void*)(uintptr_t)l,
        16, 0, 0);
}

// ---------------- prep: fp32->bf16 converts (q,k,v) + all weight transposes, one launch ------
__global__ __launch_bounds__(256) void k_prep(const float* __restrict__ query,
                                              const float* __restrict__ key,
                                              const float* __restrict__ value,
                                              const float* __restrict__ Wq,
                                              const float* __restrict__ Wk,
                                              const float* __restrict__ Wv,
                                              const float* __restrict__ Wo,
                                              u16* __restrict__ qbf,
                                              u16* __restrict__ kbf,
                                              u16* __restrict__ vbf,
                                              u16* __restrict__ Wt,
                                              u16* __restrict__ Wot) {
    __shared__ float tile[32][33];
    int x = blockIdx.x;
    if (x < 24576) {
        const float* in; u16* out;
        if (x < 8192)       { in = query; out = qbf; }
        else if (x < 16384) { in = key;   out = kbf; x -= 8192; }
        else                { in = value; out = vbf; x -= 16384; }
        const int i = x * 256 + threadIdx.x;
        float4 v = ((const float4*)in)[i];
        uint2 o;
        o.x = (unsigned)f2bf(v.x) | ((unsigned)f2bf(v.y) << 16);
        o.y = (unsigned)f2bf(v.z) | ((unsigned)f2bf(v.w) << 16);
        ((uint2*)out)[i] = o;
        return;
    }
    const int v_ = x - 24576;            // 0..10239
    const int ty = v_ / 160;             // k-tile 0..63
    const int xt = v_ - ty * 160;        // n-tile 0..159
    const float* src; u16* dst; int N, n0;
    if (xt < 64)      { src = Wq; dst = Wt;                          N = 2048; n0 = xt * 32; }
    else if (xt < 80) { src = Wk; dst = Wt + (size_t)2048 * 2048;    N = 512;  n0 = (xt - 64) * 32; }
    else if (xt < 96) { src = Wv; dst = Wt + (size_t)2560 * 2048;    N = 512;  n0 = (xt - 80) * 32; }
    else              { src = Wo; dst = Wot;                         N = 2048; n0 = (xt - 96) * 32; }
    const int k0 = ty * 32;
    const int c = threadIdx.x & 31, r = threadIdx.x >> 5;
#pragma unroll
    for (int i = 0; i < 32; i += 8)
        tile[r + i][c] = src[(size_t)(k0 + r + i) * N + n0 + c];
    __syncthreads();
#pragma unroll
    for (int i = 0; i < 32; i += 8)
        dst[(size_t)(n0 + r + i) * 2048 + k0 + c] = f2bf(tile[c][r + i]);
}

// ================= 128x128 / BK=64 GEMM core: A double-buffered, B single-buffered ========
// 4 waves (2M x 2N), per-wave 64x64 output = acc[4][4]. LDS 48 KB -> 3 blocks/CU resident
// (768-block qkv grid = 3 x 256 = ONE generation, no tail; round-7's 64 KB dbuf had 1.5
// generations = ~25% makespan waste).
// Per K-tile t:
//   {vmcnt(0); s_barrier}        A(t),B(t) landed (collective), prior iter's reads done
//   issue A(t+1) -> Abuf^1       (readers finished at t-1, two barriers ago)
//   16 ds_read: A-frags from Abuf[cur], B-frags from Bbuf
//   {lgkmcnt(0); s_barrier}      all waves' B(t) reads in regs; vmcnt UNTOUCHED so the
//                                A(t+1) staging stays in flight across the barrier
//   issue B(t+1) -> Bbuf         (safe: every wave's B(t) ds_reads drained)
//   32 MFMA                      hides both staging streams
// Keeps round-7's proven 32-MFMA-per-waited-sync ratio (round-8 showed halving it loses).
// Staging keeps the proven per-row XOR-chunk swizzle (slot = chunk ^ (row&7), 16B chunks),
// linear LDS dest + pre-swizzled global source (0 bank conflicts measured).
__device__ __forceinline__ void gemm128_loop(const u16* __restrict__ gA,
                                             const u16* __restrict__ gB,
                                             const int K, char* smem,
                                             const int wave, const int lane,
                                             f32x4 (&acc)[4][4]) {
    const int r = lane & 15, q4 = lane >> 4;
    const int wm = (wave & 1) * 64, wn = (wave >> 1) * 64;
    u16* As = (u16*)smem;                 // 2 bufs x 16 KB
    u16* Bs = (u16*)(smem + 32768);       // 1 buf  x 16 KB

    int aoff[4], boff[4];
#pragma unroll
    for (int i = 0; i < 4; i++) {
        const int ar = wm + i * 16 + r;
        aoff[i] = ar * 64 + ((q4 ^ (ar & 7)) << 3);
        const int br = wn + i * 16 + r;
        boff[i] = br * 64 + ((q4 ^ (br & 7)) << 3);
    }

    const int nt = K >> 6;

    // 4 loads/wave/tile each: chunk i covers rows i*32 + wave*8 .. +7 (8 rows x 128 B, linear dest)
#define STG_A(buf, T) do {                                                                  \
        _Pragma("unroll")                                                                   \
        for (int i_ = 0; i_ < 4; i_++)                                                      \
            async_lds16(gA + (size_t)(i_ * 32) * K + (size_t)(T) * 64,                      \
                        smem + (buf) * 16384 + (i_ * 32 + wave * 8) * 128);                 \
    } while (0)
#define STG_B(T) do {                                                                       \
        _Pragma("unroll")                                                                   \
        for (int i_ = 0; i_ < 4; i_++)                                                      \
            async_lds16(gB + (size_t)(i_ * 32) * K + (size_t)(T) * 64,                      \
                        smem + 32768 + (i_ * 32 + wave * 8) * 128);                         \
    } while (0)

    STG_A(0, 0);
    STG_B(0);

    for (int t = 0; t < nt; t++) {
        const int cur = t & 1;
        // collective: A(t)+B(t) landed AND all waves done with previous iteration
        asm volatile("s_waitcnt vmcnt(0)\ns_barrier" ::: "memory");
        if (t + 1 < nt) STG_A(cur ^ 1, t + 1);

        const u16* Ab = As + cur * 8192;
        short8 Af[4][2], Bf[4][2];
#pragma unroll
        for (int i = 0; i < 4; i++) {
            Af[i][0] = *(const short8*)(Ab + aoff[i]);
            Af[i][1] = *(const short8*)(Ab + (aoff[i] ^ 32));
            Bf[i][0] = *(const short8*)(Bs + boff[i]);
            Bf[i][1] = *(const short8*)(Bs + (boff[i] ^ 32));
        }
        // all waves' B(t) ds_reads drained (lgkm only — A(t+1) staging stays in flight)
        asm volatile("s_waitcnt lgkmcnt(0)\ns_barrier" ::: "memory");
        if (t + 1 < nt) STG_B(t + 1);

        __builtin_amdgcn_s_setprio(1);
#pragma unroll
        for (int kk = 0; kk < 2; kk++)
#pragma unroll
            for (int i = 0; i < 4; i++)
#pragma unroll
                for (int j = 0; j < 4; j++)
                    acc[i][j] = __builtin_amdgcn_mfma_f32_16x16x32_bf16(Af[i][kk], Bf[j][kk], acc[i][j], 0, 0, 0);
        __builtin_amdgcn_s_setprio(0);
    }
#undef STG_A
#undef STG_B
}

// ---------------- fused QKV projection GEMM, 128x128 tile, 768 blocks = 3/CU, 1 generation --
// bn<16: Q-proj (RoPE+scale -> qro); bn 16..19: K-proj (RoPE -> kro); bn 20..23: V (-> vtr).
__global__ __launch_bounds__(256, 3) void k_gemm_qkv(const u16* __restrict__ qbf,
                                                     const u16* __restrict__ kbf,
                                                     const u16* __restrict__ vbf,
                                                     const u16* __restrict__ Wt,   // [3072][2048] bf16
                                                     const float* __restrict__ bq,
                                                     const float* __restrict__ bk,
                                                     const float* __restrict__ bv,
                                                     const float* __restrict__ fc,
                                                     const float* __restrict__ fs,
                                                     u16* __restrict__ qro,
                                                     u16* __restrict__ kro,
                                                     u16* __restrict__ vtr) {
    __shared__ char smem[49152];
    const int tid = threadIdx.x;
    const int lane = tid & 63, wave = tid >> 6;
    const int r = lane & 15, q4 = lane >> 4;
    const int wm = (wave & 1) * 64, wn = (wave >> 1) * 64;

    // XCD-chunked bijective remap: 768 blocks = 8 XCDs x 96 (bx-fastest: A-panel L2 reuse)
    const int linear = blockIdx.y * 24 + blockIdx.x;
    const int nb = (linear & 7) * 96 + (linear >> 3);
    const int bn = nb % 24;
    const int bm = (nb / 24) * 128;

    const u16* A = (bn < 16) ? qbf : (bn < 20) ? kbf : vbf;

    const int srow = wave * 8 + (lane >> 3);
    const int c0 = ((lane & 7) ^ (lane >> 3)) * 8;
    const u16* gA = A  + (size_t)(bm + srow) * 2048 + c0;
    const u16* gB = Wt + (size_t)(bn * 128 + srow) * 2048 + c0;

    f32x4 acc[4][4] = {};
    gemm128_loop(gA, gB, 2048, smem, wave, lane, acc);

    // all waves done reading LDS before ep-scratch aliasing
    __syncthreads();

    // ---------------- fused epilogues (proven round-0 geometry) ------
    float* Ep = (float*)smem;
    if (bn < 20) {
        const bool isQ = (bn < 16);
        const float qsc = isQ ? 0.08838834764831845f * 1.4426950408889634f : 1.0f;
        const float* bias = isQ ? bq : bk;
        const int head = isQ ? bn : (bn - 16);
        u16* base = isQ ? qro : kro;
        const int nheads = isQ ? NH : NKV;

        float* ep = Ep + wave * 1280;           // 64 rows x 20 words (2-way on write = free)
        const int rowg = bm + wm + lane;        // this lane's s-row (read phase)
        const int s = rowg & 2047, bidx = rowg >> 11;
        const float* fcp0 = fc + s * 64;
        const float* fsp0 = fs + s * 64;

#pragma unroll
        for (int j = 0; j < 4; j++) {
            const float bcol = bias[head * 128 + wn + j * 16 + r];
#pragma unroll
            for (int i = 0; i < 4; i++)
#pragma unroll
                for (int g = 0; g < 4; g++)
                    ep[(i * 16 + q4 * 4 + g) * 20 + r] = acc[i][j][g] + bcol;
            float4 x0 = *(float4*)(ep + lane * 20 + 0);
            float4 x1 = *(float4*)(ep + lane * 20 + 4);
            float4 x2 = *(float4*)(ep + lane * 20 + 8);
            float4 x3 = *(float4*)(ep + lane * 20 + 12);
            const int d0 = wn + j * 16;
            const int ii0 = d0 >> 1;
            float4 ca = *(const float4*)(fcp0 + ii0);
            float4 cb = *(const float4*)(fcp0 + ii0 + 4);
            float4 sa = *(const float4*)(fsp0 + ii0);
            float4 sb = *(const float4*)(fsp0 + ii0 + 4);
            float o[16];
            o[0]  = (x0.x * ca.x - x0.y * sa.x) * qsc;  o[1]  = (x0.x * sa.x + x0.y * ca.x) * qsc;
            o[2]  = (x0.z * ca.y - x0.w * sa.y) * qsc;  o[3]  = (x0.z * sa.y + x0.w * ca.y) * qsc;
            o[4]  = (x1.x * ca.z - x1.y * sa.z) * qsc;  o[5]  = (x1.x * sa.z + x1.y * ca.z) * qsc;
            o[6]  = (x1.z * ca.w - x1.w * sa.w) * qsc;  o[7]  = (x1.z * sa.w + x1.w * ca.w) * qsc;
            o[8]  = (x2.x * cb.x - x2.y * sb.x) * qsc;  o[9]  = (x2.x * sb.x + x2.y * cb.x) * qsc;
            o[10] = (x2.z * cb.y - x2.w * sb.y) * qsc;  o[11] = (x2.z * sb.y + x2.w * cb.y) * qsc;
            o[12] = (x3.x * cb.z - x3.y * sb.z) * qsc;  o[13] = (x3.x * sb.z + x3.y * cb.z) * qsc;
            o[14] = (x3.z * cb.w - x3.w * sb.w) * qsc;  o[15] = (x3.z * sb.w + x3.w * cb.w) * qsc;
            unsigned w0 = (unsigned)f2bf(o[0])  | ((unsigned)f2bf(o[1])  << 16);
            unsigned w1 = (unsigned)f2bf(o[2])  | ((unsigned)f2bf(o[3])  << 16);
            unsigned w2 = (unsigned)f2bf(o[4])  | ((unsigned)f2bf(o[5])  << 16);
            unsigned w3 = (unsigned)f2bf(o[6])  | ((unsigned)f2bf(o[7])  << 16);
            unsigned w4 = (unsigned)f2bf(o[8])  | ((unsigned)f2bf(o[9])  << 16);
            unsigned w5 = (unsigned)f2bf(o[10]) | ((unsigned)f2bf(o[11]) << 16);
            unsigned w6 = (unsigned)f2bf(o[12]) | ((unsigned)f2bf(o[13]) << 16);
            unsigned w7 = (unsigned)f2bf(o[14]) | ((unsigned)f2bf(o[15]) << 16);
            u16* dst = base + (((size_t)(bidx * nheads + head) * SS + s) << 7) + d0;
            *(uint4*)dst = make_uint4(w0, w1, w2, w3);
            *(uint4*)(dst + 8) = make_uint4(w4, w5, w6, w7);
        }
    } else {
        // V path: convert + transpose to vtr[B][KV][D][S]
#pragma unroll
        for (int j = 0; j < 4; j++) {
            const int col = bn * 128 + wn + j * 16 + r - 2560;
            const int d = col & 127, kv = col >> 7;
            const float bb = bv[col];
#pragma unroll
            for (int i = 0; i < 4; i++) {
                const int row0 = bm + wm + i * 16 + q4 * 4;
                const int s0 = row0 & 2047, b = row0 >> 11;
                uint2 o;
                o.x = (unsigned)f2bf(acc[i][j][0] + bb) | ((unsigned)f2bf(acc[i][j][1] + bb) << 16);
                o.y = (unsigned)f2bf(acc[i][j][2] + bb) | ((unsigned)f2bf(acc[i][j][3] + bb) << 16);
                *(uint2*)(vtr + ((size_t)(b * NKV + kv) * DD + d) * SS + s0) = o;
            }
        }
    }
}

// ---------------- O-projection GEMM, 128x128 tile, 512 blocks -----
__global__ __launch_bounds__(256, 3) void k_gemm_bt(const u16* __restrict__ A,
                                                    const u16* __restrict__ Bt,
                                                    const float* __restrict__ bias,
                                                    float* __restrict__ C,
                                                    int M, int N, int K) {
    __shared__ char smem[49152];
    const int tid = threadIdx.x;
    const int lane = tid & 63, wave = tid >> 6;
    const int r = lane & 15, q4 = lane >> 4;
    const int wm = (wave & 1) * 64, wn = (wave >> 1) * 64;

    // 512 blocks = 8 XCDs x 64 chunk (bijective, bx-fastest)
    const int linear = blockIdx.y * 16 + blockIdx.x;
    const int nb = (linear & 7) * 64 + (linear >> 3);
    const int bn0 = (nb & 15) * 128;
    const int bm0 = (nb >> 4) * 128;

    const int srow = wave * 8 + (lane >> 3);
    const int c0 = ((lane & 7) ^ (lane >> 3)) * 8;
    const u16* gA = A  + (size_t)(bm0 + srow) * K + c0;
    const u16* gB = Bt + (size_t)(bn0 + srow) * K + c0;

    f32x4 acc[4][4] = {};
    gemm128_loop(gA, gB, K, smem, wave, lane, acc);

#pragma unroll
    for (int j = 0; j < 4; j++) {
        const int col = bn0 + wn + j * 16 + r;
        const float bb = bias[col];
#pragma unroll
        for (int i = 0; i < 4; i++) {
            const int row = bm0 + wm + i * 16 + q4 * 4;
#pragma unroll
            for (int g = 0; g < 4; g++)
                C[(size_t)(row + g) * N + col] = acc[i][j][g] + bb;
        }
    }
}

// ---------------- flash attention: KVBLK=64, double-buffered, 1 barrier / 64 keys ----------
// (byte-identical to round 7 — hardware-verified passing)
__global__ __launch_bounds__(256) void k_attn(const u16* __restrict__ Q,   // [B*H][S][D] (scaled)
                                              const u16* __restrict__ K_,  // [B*KV][S][D]
                                              const u16* __restrict__ V_,  // [B*KV][D][S]
                                              u16* __restrict__ Ctx) {     // [B*S][H*D]
    __shared__ u16 Ks[2][64 * 128];    // 2 x 16 KB
    __shared__ u16 Vs[2][2 * 128 * 32];// 2 x 16 KB, layout [half][d 0..127][32 keys]
    __shared__ u16 Pb[4][32 * 40];     // 10 KB, 80B row stride (free 2-way)

    const int tid = threadIdx.x;
    const int lane = tid & 63, wave = tid >> 6;
    const int bh = blockIdx.x;
    const int b = bh >> 4, h = bh & 15;
    const int kvh = (b << 2) | (h >> 2);
    const int qb = (gridDim.y - 1 - blockIdx.y) * 128;   // heavy-first
    const int qcol = lane & 15, q4 = lane >> 4;
    const int qw = qb + wave * 32;

    const u16* Qg = Q + ((size_t)bh * SS + qw + qcol) * DD;
    short8 qfr[2][4];
#pragma unroll
    for (int qi = 0; qi < 2; qi++)
#pragma unroll
        for (int c = 0; c < 4; c++)
            qfr[qi][c] = *(const short8*)(Qg + qi * 16 * DD + c * 32 + q4 * 8);

    const u16* Kg = K_ + (size_t)kvh * SS * DD;
    const u16* Vg = V_ + (size_t)kvh * DD * SS;

    const int krow = tid >> 4;                    // 0..15 across block (4 rows/wave/load)
    const int kchunk = (tid & 15) ^ (krow & 7);
    const int vd = tid >> 2;                      // 0..63 (16 d-rows/wave/load)
    const int vchunk = (tid & 3) ^ ((vd >> 1) & 3);

    const int nt = (qb + 128) >> 6;
    const int kmax = (nt - 1) * 64;               // clamp prefetch (stay in-bounds)

    f32x4 lacc[2] = {};
    f32x4 oacc[2][8] = {};

    const short8 ones = {0x3F80, 0x3F80, 0x3F80, 0x3F80, 0x3F80, 0x3F80, 0x3F80, 0x3F80};
    u16* pb = &Pb[wave][0];
    unsigned* pb32 = (unsigned*)pb;

    // 8 loads/wave: K rows {0,16,32,48}+krow ; V (half,dblk) x {16 d-rows, 32 keys}
#define STAGE_KV(T, BUF) do {                                                                   \
        const int kb_ = min((T) * 64, kmax);                                                    \
        async_lds16(Kg + (size_t)(kb_ + krow) * DD + kchunk * 8,        &Ks[BUF][0] + wave * 512);        \
        async_lds16(Kg + (size_t)(kb_ + 16 + krow) * DD + kchunk * 8,   &Ks[BUF][0] + 2048 + wave * 512); \
        async_lds16(Kg + (size_t)(kb_ + 32 + krow) * DD + kchunk * 8,   &Ks[BUF][0] + 4096 + wave * 512); \
        async_lds16(Kg + (size_t)(kb_ + 48 + krow) * DD + kchunk * 8,   &Ks[BUF][0] + 6144 + wave * 512); \
        async_lds16(Vg + (size_t)vd * SS + kb_ + vchunk * 8,            &Vs[BUF][0] + wave * 512);        \
        async_lds16(Vg + (size_t)vd * SS + kb_ + 32 + vchunk * 8,       &Vs[BUF][0] + 4096 + wave * 512); \
        async_lds16(Vg + (size_t)(vd + 64) * SS + kb_ + vchunk * 8,     &Vs[BUF][0] + 2048 + wave * 512); \
        async_lds16(Vg + (size_t)(vd + 64) * SS + kb_ + 32 + vchunk * 8,&Vs[BUF][0] + 6144 + wave * 512); \
    } while (0)

    STAGE_KV(0, 0);

    for (int t = 0; t < nt; t++) {
        const int kb = t * 64;
        const int cur = t & 1;
        // collective: all waves' tile-t loads landed AND all done computing t-1
        asm volatile("s_waitcnt vmcnt(0)\n\ts_barrier" ::: "memory");
        if (t + 1 < nt) STAGE_KV(t + 1, cur ^ 1);

#pragma unroll
        for (int hh = 0; hh < 2; hh++) {
            const int kbh = kb + hh * 32;
            if (kbh <= qw + 31) {                      // wave-uniform causal skip
                const u16* Ksc = &Ks[cur][hh * 32 * 128];
                const u16* Vsc = &Vs[cur][hh * 4096];

                f32x4 sc[2][2] = {};
                __builtin_amdgcn_s_setprio(1);
#pragma unroll
                for (int kt = 0; kt < 2; kt++) {
                    const int kr = kt * 16 + qcol;
#pragma unroll
                    for (int c = 0; c < 4; c++) {
                        short8 kf = *(const short8*)(Ksc + kr * 128 + (((c * 4 + q4) ^ (kr & 7)) << 3));
                        sc[kt][0] = __builtin_amdgcn_mfma_f32_16x16x32_bf16(kf, qfr[0][c], sc[kt][0], 0, 0, 0);
                        sc[kt][1] = __builtin_amdgcn_mfma_f32_16x16x32_bf16(kf, qfr[1][c], sc[kt][1], 0, 0, 0);
                    }
                }
                __builtin_amdgcn_s_setprio(0);

                if (kbh + 32 > qw) {                   // diagonal halves only
#pragma unroll
                    for (int kt = 0; kt < 2; kt++)
#pragma unroll
                        for (int qi = 0; qi < 2; qi++)
#pragma unroll
                            for (int g = 0; g < 4; g++) {
                                const int key = kbh + kt * 16 + q4 * 4 + g;
                                if (key > qw + qi * 16 + qcol) sc[kt][qi][g] = -1e30f;
                            }
                }

                const unsigned sel = 0x07060302u;
#pragma unroll
                for (int qi = 0; qi < 2; qi++) {
                    float p0 = EXP2(sc[0][qi][0]), p1 = EXP2(sc[0][qi][1]);
                    float p2 = EXP2(sc[0][qi][2]), p3 = EXP2(sc[0][qi][3]);
                    float p4 = EXP2(sc[1][qi][0]), p5 = EXP2(sc[1][qi][1]);
                    float p6 = EXP2(sc[1][qi][2]), p7 = EXP2(sc[1][qi][3]);
                    unsigned pk0 = __builtin_amdgcn_perm(__float_as_uint(p1), __float_as_uint(p0), sel);
                    unsigned pk1 = __builtin_amdgcn_perm(__float_as_uint(p3), __float_as_uint(p2), sel);
                    unsigned pk2 = __builtin_amdgcn_perm(__float_as_uint(p5), __float_as_uint(p4), sel);
                    unsigned pk3 = __builtin_amdgcn_perm(__float_as_uint(p7), __float_as_uint(p6), sel);
                    const int row = qi * 16 + qcol;
                    *(uint2*)(pb32 + row * 20 + 2 * q4)     = make_uint2(pk0, pk1);
                    *(uint2*)(pb32 + row * 20 + 8 + 2 * q4) = make_uint2(pk2, pk3);
                }

                short8 pf0 = *(const short8*)(pb + qcol * 40 + q4 * 8);
                short8 pf1 = *(const short8*)(pb + (16 + qcol) * 40 + q4 * 8);

                __builtin_amdgcn_s_setprio(1);
                lacc[0] = __builtin_amdgcn_mfma_f32_16x16x32_bf16(ones, pf0, lacc[0], 0, 0, 0);
                lacc[1] = __builtin_amdgcn_mfma_f32_16x16x32_bf16(ones, pf1, lacc[1], 0, 0, 0);
#pragma unroll
                for (int dt = 0; dt < 8; dt++) {
                    const int vr = dt * 16 + qcol;
                    short8 vfr = *(const short8*)(Vsc + vr * 32 + ((q4 ^ ((vr >> 1) & 3)) << 3));
                    oacc[0][dt] = __builtin_amdgcn_mfma_f32_16x16x32_bf16(vfr, pf0, oacc[0][dt], 0, 0, 0);
                    oacc[1][dt] = __builtin_amdgcn_mfma_f32_16x16x32_bf16(vfr, pf1, oacc[1][dt], 0, 0, 0);
                }
                __builtin_amdgcn_s_setprio(0);
            }
        }
    }
#undef STAGE_KV

#pragma unroll
    for (int qi = 0; qi < 2; qi++) {
        const float inv = 1.0f / lacc[qi][0];
        u16* outp = Ctx + ((size_t)b * SS + qw + qi * 16 + qcol) * (NH * DD) + h * DD;
#pragma unroll
        for (int dt = 0; dt < 8; dt++) {
            unsigned lo = (unsigned)f2bf(oacc[qi][dt][0] * inv) | ((unsigned)f2bf(oacc[qi][dt][1] * inv) << 16);
            unsigned hi = (unsigned)f2bf(oacc[qi][dt][2] * inv) | ((unsigned)f2bf(oacc[qi][dt][3] * inv) << 16);
            *(uint2*)(outp + dt * 16 + q4 * 4) = make_uint2(lo, hi);
        }
    }
}

extern "C" void kernel_launch(void* const* d_in, const int* in_sizes, int n_in,
                              void* d_out, int out_size, void* d_ws, size_t ws_size,
                              hipStream_t stream) {
    const float* query = (const float*)d_in[0];
    const float* key   = (const float*)d_in[1];
    const float* value = (const float*)d_in[2];
    const float* fc    = (const float*)d_in[4];
    const float* fs    = (const float*)d_in[5];
    const float* Wq    = (const float*)d_in[6];
    const float* bq    = (const float*)d_in[7];
    const float* Wk    = (const float*)d_in[8];
    const float* bk    = (const float*)d_in[9];
    const float* Wv    = (const float*)d_in[10];
    const float* bv    = (const float*)d_in[11];
    const float* Wo    = (const float*)d_in[12];
    const float* bo    = (const float*)d_in[13];
    float* out = (float*)d_out;

    char* w = (char*)d_ws;
    u16* qbf = (u16*)(w);                    // 16 MB  bf16 query [4096][2048]
    u16* kbf = (u16*)(w + 16777216);         // 16 MB
    u16* vbf = (u16*)(w + 33554432);         // 16 MB
    u16* Wt  = (u16*)(w + 50331648);         // 12 MB  [Wq|Wk|Wv]^T bf16 [3072][2048]
    u16* Wot = (u16*)(w + 62914560);         //  8 MB  Wo^T bf16 [2048][2048]
    u16* qro = (u16*)(w + 71303168);         // 16 MB  roped+scaled q bf16 [B][H][S][D]
    u16* kro = (u16*)(w + 88080384);         //  4 MB  roped k bf16 [B][KV][S][D]
    u16* vtr = (u16*)(w + 92274688);         //  4 MB  v bf16 [B][KV][D][S]
    u16* ctx = (u16*)(w + 96468992);         // 16 MB  ctx bf16 [4096][2048]  (end 108 MB)

    k_prep<<<34816, 256, 0, stream>>>(query, key, value, Wq, Wk, Wv, Wo,
                                      qbf, kbf, vbf, Wt, Wot);
    k_gemm_qkv<<<dim3(24, 32), 256, 0, stream>>>(qbf, kbf, vbf, Wt, bq, bk, bv,
                                                 fc, fs, qro, kro, vtr);
    k_attn<<<dim3(32, 16), 256, 0, stream>>>(qro, kro, vtr, ctx);
    k_gemm_bt<<<dim3(16, 32), 256, 0, stream>>>(ctx, Wot, bo, out, 4096, 2048, 2048);
}